// Round 1
// 344.914 us; speedup vs baseline: 1.2645x; 1.2645x over previous
//
#include <hip/hip_runtime.h>

// ============================================================================
// CrossAttention fused: qkv proj (bf16 MFMA) -> flash attn -> out proj + bias
// B=2, NQ=2048, NK=4096, D=1024, H=16, HD=64, SCALE=0.125, mask-then-scale
//
// attn_k v2: swapped QK^T (S^T, k lane-local) -> in-register softmax (2 shfls),
// P feeds PV directly as 16x16x16 B-operand (no LDS round-trip), Vt 72-pad +
// XOR swizzle (conflict-free transpose stores), reg-staged KV prefetch (T14),
// XCD-aware block swizzle (T1), setprio around MFMA (T5), exp2-domain softmax.
// ============================================================================

typedef __attribute__((ext_vector_type(8))) short bf16x8;
typedef __attribute__((ext_vector_type(4))) short bf16x4;
typedef __attribute__((ext_vector_type(4))) float f32x4;
typedef __attribute__((ext_vector_type(4))) unsigned short u16x4;
typedef unsigned short u16;
typedef unsigned char u8;

#define DEV __device__ __forceinline__

DEV u16 f2bf(float f) {
  union { float f; unsigned int u; } x; x.f = f;
  unsigned int u = x.u;
  return (u16)((u + 0x7fffu + ((u >> 16) & 1u)) >> 16);
}

DEV unsigned cvt_pk_bf16(float lo, float hi) {
  unsigned r;
  asm("v_cvt_pk_bf16_f32 %0, %1, %2" : "=v"(r) : "v"(lo), "v"(hi));
  return r;
}

// mask-then-scale in log2 domain: bias = -1e20 * 0.125 * log2(e)
#define MASK_BIAS (-1.8033688e19f)
#define SCALE_LOG2E 0.18033688f

// ---------------------------------------------------------------------------
// Mask decode: fingerprint storage dtype (u8/bool vs int32 vs f32 vs bf16)
// and expand to f32 additive bias (MASK_BIAS if masked, 0 otherwise).
// ---------------------------------------------------------------------------
__global__ void decode_mask_k(const u8* __restrict__ raw, float* __restrict__ biasf, int n) {
  int t = threadIdx.x;
  int f_off = 0, f_gt1 = 0, f_80 = 0;
  for (int i = t; i < n; i += 256) {
    u8 bv = raw[i];
    if (bv > 1) f_gt1 = 1;
    if ((i & 3) && bv) f_off = 1;
    if (((i & 3) == 0) && bv == 0x80) f_80 = 1;
  }
  int g_gt1 = __syncthreads_or(f_gt1);
  int g_off = __syncthreads_or(f_off);
  int g_80  = __syncthreads_or(f_80);
  for (int i = t; i < n; i += 256) {
    int v;
    if (g_gt1) {
      if (g_80) v = (((const u16*)raw)[i] != 0) ? 1 : 0;      // bf16 storage
      else      v = (((const float*)raw)[i] != 0.0f) ? 1 : 0; // f32 storage
    } else if (g_off) {
      v = raw[i] ? 1 : 0;                                     // bool/u8 storage
    } else {
      v = (((const int*)raw)[i] != 0) ? 1 : 0;                // int32 storage
    }
    biasf[i] = v ? MASK_BIAS : 0.0f;
  }
}

// ---------------------------------------------------------------------------
// Projection GEMM: C = A(fp32 MxK) * W(fp32 NxK)^T, output bf16 in head layout
// [b, h, seq, 64].  M = B*seq, K = N = 1024. 128x128 tile, BK=32, 4 waves.
// ---------------------------------------------------------------------------
__global__ __launch_bounds__(256) void proj_gemm(
    const float* __restrict__ A, const float* __restrict__ W,
    u16* __restrict__ outh, int sl /* log2(seq) */)
{
  constexpr int K = 1024;
  __shared__ __align__(16) u16 As[128][40];
  __shared__ __align__(16) u16 Bs[128][40];
  const int tid = threadIdx.x;
  const int lane = tid & 63;
  const int w = tid >> 6;
  const int wm = w >> 1, wn = w & 1;
  const int bm = blockIdx.x, bn = blockIdx.y;
  const int l15 = lane & 15, lg = lane >> 4;

  f32x4 acc[4][4] = {};

  for (int k0 = 0; k0 < K; k0 += 32) {
    __syncthreads();
#pragma unroll
    for (int i = 0; i < 4; ++i) {
      int f = tid + 256 * i;       // float4 index within 128x32 tile
      int row = f >> 3, c4 = f & 7;
      float4 va = *reinterpret_cast<const float4*>(A + (size_t)(bm * 128 + row) * K + k0 + c4 * 4);
      u16x4 sa; sa[0] = f2bf(va.x); sa[1] = f2bf(va.y); sa[2] = f2bf(va.z); sa[3] = f2bf(va.w);
      *reinterpret_cast<u16x4*>(&As[row][c4 * 4]) = sa;
      float4 vb = *reinterpret_cast<const float4*>(W + (size_t)(bn * 128 + row) * K + k0 + c4 * 4);
      u16x4 sb; sb[0] = f2bf(vb.x); sb[1] = f2bf(vb.y); sb[2] = f2bf(vb.z); sb[3] = f2bf(vb.w);
      *reinterpret_cast<u16x4*>(&Bs[row][c4 * 4]) = sb;
    }
    __syncthreads();
    bf16x8 af[4], bfr[4];
#pragma unroll
    for (int mi = 0; mi < 4; ++mi)
      af[mi] = *reinterpret_cast<const bf16x8*>(&As[wm * 64 + mi * 16 + l15][lg * 8]);
#pragma unroll
    for (int ni = 0; ni < 4; ++ni)
      bfr[ni] = *reinterpret_cast<const bf16x8*>(&Bs[wn * 64 + ni * 16 + l15][lg * 8]);
#pragma unroll
    for (int mi = 0; mi < 4; ++mi)
#pragma unroll
      for (int ni = 0; ni < 4; ++ni)
        acc[mi][ni] = __builtin_amdgcn_mfma_f32_16x16x32_bf16(af[mi], bfr[ni], acc[mi][ni], 0, 0, 0);
  }

  const int seqmask = (1 << sl) - 1;
#pragma unroll
  for (int mi = 0; mi < 4; ++mi)
#pragma unroll
    for (int ni = 0; ni < 4; ++ni)
#pragma unroll
      for (int r = 0; r < 4; ++r) {
        int m = bm * 128 + wm * 64 + mi * 16 + lg * 4 + r;
        int n = bn * 128 + wn * 64 + ni * 16 + l15;
        int b = m >> sl, ml = m & seqmask;
        int h = n >> 6, hd = n & 63;
        outh[((((size_t)b * 16 + h) << sl) + ml) * 64 + hd] = f2bf(acc[mi][ni][r]);
      }
}

// ---------------------------------------------------------------------------
// Flash attention v2. 1 block = (b, h, 64-row q-tile); 4 waves x 16 q-rows.
// KV tiles of 64. Swapped QK^T: S^T[k][q], q = l15 (lane-local row).
// K row-major [64][72]; V transposed Vt[d][key] [64][72] + XOR swizzle.
// ---------------------------------------------------------------------------
__global__ __launch_bounds__(256) void attn_k(
    const u16* __restrict__ qh, const u16* __restrict__ kh, const u16* __restrict__ vh,
    const float* __restrict__ biasf, u16* __restrict__ ao)
{
  __shared__ __align__(16) u16 Qs[64][72];
  __shared__ __align__(16) u16 Ks[64][72];
  __shared__ __align__(16) u16 Vt[64 * 72];   // [d][key], byte ^= ((d>>3)&7)<<4

  const int tid = threadIdx.x;
  const int lane = tid & 63;
  const int w = tid >> 6;
  const int l15 = lane & 15, lg = lane >> 4;

  // XCD-aware swizzle: 1024 blocks, 8 XCDs -> each XCD owns 128 consecutive
  // work items = 4 (b,h) panels -> KV slices (4 MB) fit that XCD's L2.
  int bid = blockIdx.x;
  bid = (bid & 7) * 128 + (bid >> 3);
  const int qt = bid & 31;       // 32 q-tiles of 64 rows
  const int bh = bid >> 5;       // 0..31 = b*16 + h
  const int b = bh >> 4, h = bh & 15;

  const size_t base_q = ((size_t)bh * 2048 + (size_t)qt * 64) * 64;
  const size_t base_kv = (size_t)bh * 4096 * 64;
  const float* bp = biasf + b * 4096;

  // stage Q (once)
#pragma unroll
  for (int i = 0; i < 2; ++i) {
    int f = tid + 256 * i;
    int row = f >> 3, c8 = f & 7;
    *reinterpret_cast<uint4*>(&Qs[row][c8 * 8]) =
        *reinterpret_cast<const uint4*>(qh + base_q + (size_t)f * 8);
  }
  __syncthreads();

  // Q fragment: B-operand of swapped QK^T (B[d][q=l15])
  bf16x8 qf[2];
#pragma unroll
  for (int kk = 0; kk < 2; ++kk)
    qf[kk] = *reinterpret_cast<const bf16x8*>(&Qs[w * 16 + l15][kk * 32 + lg * 8]);

  f32x4 o[4] = {};                 // O^T[d = dt*16+lg*4+r][q = l15]
  float mrow = -INFINITY, lrow = 0.f;

  const int kp = tid >> 3, c8v = tid & 7;  // V transpose-stage assignment

  // prefetch tile 0 into registers (T14 reg-staged)
  uint4 kr0 = *reinterpret_cast<const uint4*>(kh + base_kv + (size_t)tid * 8);
  uint4 kr1 = *reinterpret_cast<const uint4*>(kh + base_kv + (size_t)(tid + 256) * 8);
  uint4 vr0 = *reinterpret_cast<const uint4*>(vh + base_kv + (size_t)(2 * kp) * 64 + c8v * 8);
  uint4 vr1 = *reinterpret_cast<const uint4*>(vh + base_kv + (size_t)(2 * kp + 1) * 64 + c8v * 8);

  for (int t = 0; t < 64; ++t) {
    __syncthreads();   // all waves done reading LDS of previous tile
    // ---- write staged tile into LDS ----
    {
      int f0 = tid, f1 = tid + 256;
      *reinterpret_cast<uint4*>(&Ks[f0 >> 3][(f0 & 7) * 8]) = kr0;
      *reinterpret_cast<uint4*>(&Ks[f1 >> 3][(f1 & 7) * 8]) = kr1;
      const u16* pa = reinterpret_cast<const u16*>(&vr0);
      const u16* pb = reinterpret_cast<const u16*>(&vr1);
#pragma unroll
      for (int j = 0; j < 8; ++j) {
        ushort2 t2; t2.x = pa[j]; t2.y = pb[j];
        int row = c8v * 8 + j;               // d
        int byteoff = row * 144 + kp * 4;    // col = 2*kp keys
        byteoff ^= ((row >> 3) & 7) << 4;    // swizzle: conflict-free stores
        *reinterpret_cast<ushort2*>(reinterpret_cast<char*>(Vt) + byteoff) = t2;
      }
    }
    // ---- issue next tile's global loads (overlap with compute below) ----
    if (t < 63) {
      size_t nb = base_kv + (size_t)(t + 1) * 4096;
      kr0 = *reinterpret_cast<const uint4*>(kh + nb + (size_t)tid * 8);
      kr1 = *reinterpret_cast<const uint4*>(kh + nb + (size_t)(tid + 256) * 8);
      vr0 = *reinterpret_cast<const uint4*>(vh + nb + (size_t)(2 * kp) * 64 + c8v * 8);
      vr1 = *reinterpret_cast<const uint4*>(vh + nb + (size_t)(2 * kp + 1) * 64 + c8v * 8);
    }
    __syncthreads();

    const int kv0 = t * 64;

    // ---- S^T = K Q^T : row = k (lg*4+r within n-tile), col = q = l15 ----
    f32x4 s[4];
    __builtin_amdgcn_s_setprio(1);
#pragma unroll
    for (int n = 0; n < 4; ++n) {
      f32x4 z = {};
      bf16x8 k0f = *reinterpret_cast<const bf16x8*>(&Ks[n * 16 + l15][lg * 8]);
      bf16x8 k1f = *reinterpret_cast<const bf16x8*>(&Ks[n * 16 + l15][32 + lg * 8]);
      z = __builtin_amdgcn_mfma_f32_16x16x32_bf16(k0f, qf[0], z, 0, 0, 0);
      z = __builtin_amdgcn_mfma_f32_16x16x32_bf16(k1f, qf[1], z, 0, 0, 0);
      s[n] = z;
    }
    __builtin_amdgcn_s_setprio(0);

    // ---- mask+scale folded to one FMA (log2 domain), lane-local max ----
    float mt = -INFINITY;
#pragma unroll
    for (int n = 0; n < 4; ++n) {
      float4 bv = *reinterpret_cast<const float4*>(bp + kv0 + n * 16 + lg * 4);
      s[n][0] = fmaf(s[n][0], SCALE_LOG2E, bv.x);
      s[n][1] = fmaf(s[n][1], SCALE_LOG2E, bv.y);
      s[n][2] = fmaf(s[n][2], SCALE_LOG2E, bv.z);
      s[n][3] = fmaf(s[n][3], SCALE_LOG2E, bv.w);
      mt = fmaxf(mt, fmaxf(fmaxf(s[n][0], s[n][1]), fmaxf(s[n][2], s[n][3])));
    }
    // reduce over k: only across the 4 lg groups (q = l15 is lane-local)
    mt = fmaxf(mt, __shfl_xor(mt, 16, 64));
    mt = fmaxf(mt, __shfl_xor(mt, 32, 64));
    float mnew = fmaxf(mrow, mt);
    float alpha = __builtin_amdgcn_exp2f(mrow - mnew);
    mrow = mnew;
    float rs = 0.f;
#pragma unroll
    for (int n = 0; n < 4; ++n)
#pragma unroll
      for (int r = 0; r < 4; ++r) {
        float p = __builtin_amdgcn_exp2f(s[n][r] - mrow);
        s[n][r] = p;
        rs += p;
      }
    rs += __shfl_xor(rs, 16, 64);
    rs += __shfl_xor(rs, 32, 64);
    lrow = lrow * alpha + rs;

#pragma unroll
    for (int dt = 0; dt < 4; ++dt) {
      o[dt][0] *= alpha; o[dt][1] *= alpha; o[dt][2] *= alpha; o[dt][3] *= alpha;
    }

    // ---- P -> bf16: S^T C-layout (k=lg*4+r) IS the 16x16x16 B-layout ----
    bf16x4 pbf[4];
#pragma unroll
    for (int n = 0; n < 4; ++n) {
      union { unsigned u[2]; bf16x4 v; } uu;
      uu.u[0] = cvt_pk_bf16(s[n][0], s[n][1]);
      uu.u[1] = cvt_pk_bf16(s[n][2], s[n][3]);
      pbf[n] = uu.v;
    }

    // ---- O^T += V^T P^T  (16x16x16: A = V^T frag, B = P^T frag) ----
    __builtin_amdgcn_s_setprio(1);
#pragma unroll
    for (int dt = 0; dt < 4; ++dt) {
#pragma unroll
      for (int n = 0; n < 4; ++n) {
        int row = dt * 16 + l15;                       // d
        int byteoff = row * 144 + (n * 16 + lg * 4) * 2;
        byteoff ^= ((row >> 3) & 7) << 4;
        bf16x4 va = *reinterpret_cast<const bf16x4*>(reinterpret_cast<char*>(Vt) + byteoff);
        o[dt] = __builtin_amdgcn_mfma_f32_16x16x16bf16_1k(va, pbf[n], o[dt], 0, 0, 0);
      }
    }
    __builtin_amdgcn_s_setprio(0);
  }

  // ---- epilogue: normalize, transpose O^T -> O via retired Qs, store ----
  float rl = __builtin_amdgcn_rcpf(lrow);
#pragma unroll
  for (int dt = 0; dt < 4; ++dt) {
    unsigned p0 = cvt_pk_bf16(o[dt][0] * rl, o[dt][1] * rl);
    unsigned p1 = cvt_pk_bf16(o[dt][2] * rl, o[dt][3] * rl);
    *reinterpret_cast<unsigned*>(&Qs[w * 16 + l15][dt * 16 + lg * 4]) = p0;
    *reinterpret_cast<unsigned*>(&Qs[w * 16 + l15][dt * 16 + lg * 4 + 2]) = p1;
  }
  asm volatile("s_waitcnt lgkmcnt(0)" ::: "memory");  // wave-local: no barrier
  {
    int qr = lane >> 2, dc = (lane & 3) * 16;
    uint4 x0 = *reinterpret_cast<const uint4*>(&Qs[w * 16 + qr][dc]);
    uint4 x1 = *reinterpret_cast<const uint4*>(&Qs[w * 16 + qr][dc + 8]);
    u16* dst = ao + ((size_t)b * 2048 + qt * 64 + w * 16 + qr) * 1024 + h * 64 + dc;
    *reinterpret_cast<uint4*>(dst) = x0;
    *reinterpret_cast<uint4*>(dst + 8) = x1;
  }
}

// ---------------------------------------------------------------------------
// Output GEMM: out = Abf(bf16 4096x1024) * Wp(fp32 1024x1024)^T + bp, fp32 out
// ---------------------------------------------------------------------------
__global__ __launch_bounds__(256) void out_gemm(
    const u16* __restrict__ Abf, const float* __restrict__ W,
    const float* __restrict__ bias, float* __restrict__ out)
{
  constexpr int K = 1024, N = 1024;
  __shared__ __align__(16) u16 As[128][40];
  __shared__ __align__(16) u16 Bs[128][40];
  const int tid = threadIdx.x;
  const int lane = tid & 63;
  const int w = tid >> 6;
  const int wm = w >> 1, wn = w & 1;
  const int bm = blockIdx.x, bn = blockIdx.y;
  const int l15 = lane & 15, lg = lane >> 4;

  f32x4 acc[4][4] = {};

  for (int k0 = 0; k0 < K; k0 += 32) {
    __syncthreads();
#pragma unroll
    for (int i = 0; i < 2; ++i) {
      int f = tid + 256 * i;       // u16x8 chunk index, 128 rows x 4 chunks
      int row = f >> 2, c8 = f & 3;
      *reinterpret_cast<uint4*>(&As[row][c8 * 8]) =
          *reinterpret_cast<const uint4*>(Abf + (size_t)(bm * 128 + row) * K + k0 + c8 * 8);
    }
#pragma unroll
    for (int i = 0; i < 4; ++i) {
      int f = tid + 256 * i;
      int row = f >> 3, c4 = f & 7;
      float4 vb = *reinterpret_cast<const float4*>(W + (size_t)(bn * 128 + row) * K + k0 + c4 * 4);
      u16x4 sb; sb[0] = f2bf(vb.x); sb[1] = f2bf(vb.y); sb[2] = f2bf(vb.z); sb[3] = f2bf(vb.w);
      *reinterpret_cast<u16x4*>(&Bs[row][c4 * 4]) = sb;
    }
    __syncthreads();
    bf16x8 af[4], bfr[4];
#pragma unroll
    for (int mi = 0; mi < 4; ++mi)
      af[mi] = *reinterpret_cast<const bf16x8*>(&As[wm * 64 + mi * 16 + l15][lg * 8]);
#pragma unroll
    for (int ni = 0; ni < 4; ++ni)
      bfr[ni] = *reinterpret_cast<const bf16x8*>(&Bs[wn * 64 + ni * 16 + l15][lg * 8]);
#pragma unroll
    for (int mi = 0; mi < 4; ++mi)
#pragma unroll
      for (int ni = 0; ni < 4; ++ni)
        acc[mi][ni] = __builtin_amdgcn_mfma_f32_16x16x32_bf16(af[mi], bfr[ni], acc[mi][ni], 0, 0, 0);
  }

#pragma unroll
  for (int mi = 0; mi < 4; ++mi)
#pragma unroll
    for (int ni = 0; ni < 4; ++ni)
#pragma unroll
      for (int r = 0; r < 4; ++r) {
        int m = bm * 128 + wm * 64 + mi * 16 + lg * 4 + r;
        int n = bn * 128 + wn * 64 + ni * 16 + l15;
        out[(size_t)m * N + n] = acc[mi][ni][r] + bias[n];
      }
}

// ---------------------------------------------------------------------------
extern "C" void kernel_launch(void* const* d_in, const int* in_sizes, int n_in,
                              void* d_out, int out_size, void* d_ws, size_t ws_size,
                              hipStream_t stream) {
  const float* q  = (const float*)d_in[0];
  const float* k  = (const float*)d_in[1];
  const float* v  = (const float*)d_in[2];
  const u8* mask_raw = (const u8*)d_in[3];
  const float* Wq = (const float*)d_in[4];
  const float* Wk = (const float*)d_in[5];
  const float* Wv = (const float*)d_in[6];
  const float* Wp = (const float*)d_in[7];
  const float* bp = (const float*)d_in[8];
  float* out = (float*)d_out;

  char* ws = (char*)d_ws;
  u16* qh = (u16*)(ws);                    //  8 MB: [2,16,2048,64] bf16
  u16* kh = (u16*)(ws + 8388608);          // 16 MB: [2,16,4096,64] bf16
  u16* vh = (u16*)(ws + 25165824);         // 16 MB: [2,16,4096,64] bf16
  u16* ao = (u16*)(ws + 41943040);         //  8 MB: [2,2048,1024] bf16
  float* biasf = (float*)(ws + 50331648);  // 32 KB: decoded mask bias (f32)

  decode_mask_k<<<1, 256, 0, stream>>>(mask_raw, biasf, 8192);
  proj_gemm<<<dim3(32, 8), 256, 0, stream>>>(q, Wq, qh, 11);
  proj_gemm<<<dim3(64, 8), 256, 0, stream>>>(k, Wk, kh, 12);
  proj_gemm<<<dim3(64, 8), 256, 0, stream>>>(v, Wv, vh, 12);
  attn_k<<<1024, 256, 0, stream>>>(qh, kh, vh, biasf, ao);
  out_gemm<<<dim3(32, 8), 256, 0, stream>>>(ao, Wp, bp, out);
}